// Round 6
// baseline (18.965 us; speedup 1.0000x reference)
//
#include <hip/hip_runtime.h>

// KAN activation: out[b,o,i] = sum_t B_t(x[b,i]) * coef[o,i,t]
// B=2048, IN=OUT=64, uniform knots (15), order k=3, 11 basis funcs.
//
// Round-6 thesis: rounds 2/4/5 (14.7-15.8us) were serialization-bound, not
// pipe-bound -- each block was a latency chain (loads -> VALU -> LDS -> barrier
// -> LDS -> stores) executing ~serially per CU. This version makes every wave
// an independent streaming pipeline (memset-like):
//   - ONE barrier, immediately after a coalesced coef stage (no dependent
//     compute before it).
//   - Each thread computes its OWN bases per row (redundant x4 o-groups; VALU
//     is cheap) -- no bases LDS, no scatter, no mid-kernel barrier.
//   - Dense 11-vector built in REGISTERS via a 4-way select chain (handles
//     out-of-range x for free: d outside [0,3] -> 0), so the 11-term dot uses
//     compile-time register indices.
//   - 8-row streaming loop per thread: load x (coalesced) -> 18 VALU weights
//     -> 88 select -> 44 FMA -> 4 coalesced stores. No inter-row dependencies.

#define BATCH    2048
#define IN_DIM   64
#define OUT_DIM  64
#define NCOEF    11
#define B_CHUNK  8
#define O_BLK    16                          // o's per block; thread owns 4
#define CTILE    (O_BLK * IN_DIM * NCOEF)    // 11264 floats = 44 KiB

__global__ __launch_bounds__(256) void kan_kernel(
    const float* __restrict__ x,     // (2048, 64)
    const float* __restrict__ grid,  // (64, 64, 15) broadcast uniform knots
    const float* __restrict__ coef,  // (64, 64, 11)
    float* __restrict__ out)         // (2048, 64, 64)
{
    __shared__ float clds[CTILE];    // 44 KiB

    const int tid    = threadIdx.x;
    const int o_tile = blockIdx.x & 3;            // 4 o-tiles of 16
    const int b0     = (blockIdx.x >> 2) * B_CHUNK;

    // ---- coef tile -> LDS: pure coalesced stride-1 copy, then ONE barrier ----
    const float* csrc = coef + (size_t)o_tile * CTILE;
    #pragma unroll
    for (int q = 0; q < CTILE / 256; ++q)
        clds[tid + q * 256] = csrc[tid + q * 256];

    const float g0    = grid[0];
    const float inv_h = 1.0f / (grid[1] - g0);

    __syncthreads();

    // ---- fill 44 coef regs (lane word-stride 11 = odd -> conflict-free) ----
    const int i    = tid & 63;
    const int ogrp = tid >> 6;                    // 0..3
    const int ol0  = ogrp * 4;                    // local o base (0,4,8,12)
    const int o0   = o_tile * O_BLK + ol0;

    float c[4][NCOEF];
    #pragma unroll
    for (int oo = 0; oo < 4; ++oo) {
        const int row = ((ol0 + oo) * IN_DIM + i) * NCOEF;
        #pragma unroll
        for (int t = 0; t < NCOEF; ++t)
            c[oo][t] = clds[row + t];
    }

    // ---- barrier-free streaming loop: 8 rows, fully independent ----
    #pragma unroll 2
    for (int bb = 0; bb < B_CHUNK; ++bb) {
        const float xv  = x[(size_t)(b0 + bb) * IN_DIM + i];
        const float pos = (xv - g0) * inv_h;          // cell coord in [0,14)
        const float fm  = floorf(pos);
        const float t   = pos - fm;
        // base = m-3; push out-of-domain lanes far away so every select -> 0
        const int   base = (pos >= 0.0f && pos < 14.0f) ? ((int)fm - 3) : -1000;

        const float t2 = t * t;
        const float t3 = t2 * t;
        const float s  = 1.0f - t;
        const float w0 = s * s * s * (1.0f / 6.0f);
        const float w1 = (3.0f * t3 - 6.0f * t2 + 4.0f) * (1.0f / 6.0f);
        const float w2 = (-3.0f * t3 + 3.0f * t2 + 3.0f * t + 1.0f) * (1.0f / 6.0f);
        const float w3 = t3 * (1.0f / 6.0f);

        // dense basis vector in registers (compile-time indices everywhere)
        float dense[NCOEF];
        #pragma unroll
        for (int tt = 0; tt < NCOEF; ++tt) {
            const int d = tt - base;
            dense[tt] = (d == 0) ? w0 : (d == 1) ? w1 : (d == 2) ? w2
                      : (d == 3) ? w3 : 0.0f;
        }

        float* op = &out[(size_t)(b0 + bb) * (OUT_DIM * IN_DIM) + o0 * IN_DIM + i];
        #pragma unroll
        for (int oo = 0; oo < 4; ++oo) {
            float acc = dense[0] * c[oo][0];
            #pragma unroll
            for (int tt = 1; tt < NCOEF; ++tt)
                acc += dense[tt] * c[oo][tt];
            op[oo * IN_DIM] = acc;
        }
    }
}

extern "C" void kernel_launch(void* const* d_in, const int* in_sizes, int n_in,
                              void* d_out, int out_size, void* d_ws, size_t ws_size,
                              hipStream_t stream) {
    const float* x    = (const float*)d_in[0];
    const float* grid = (const float*)d_in[1];
    const float* coef = (const float*)d_in[2];
    float* out = (float*)d_out;

    const int nblocks = (BATCH / B_CHUNK) * (OUT_DIM / O_BLK);  // 1024
    kan_kernel<<<nblocks, 256, 0, stream>>>(x, grid, coef, out);
}

// Round 7
// 18.944 us; speedup vs baseline: 1.0011x; 1.0011x over previous
//
#include <hip/hip_runtime.h>

// KAN activation: out[b,o,i] = sum_t B_t(x[b,i]) * coef[o,i,t]
// B=2048, IN=OUT=64, uniform knots (15), order k=3, 11 basis funcs.
//
// Round-6 thesis: rounds 2/4/5 (14.7-15.8us) were serialization-bound, not
// pipe-bound -- each block was a latency chain (loads -> VALU -> LDS -> barrier
// -> LDS -> stores) executing ~serially per CU. This version makes every wave
// an independent streaming pipeline (memset-like):
//   - ONE barrier, immediately after a coalesced coef stage (no dependent
//     compute before it).
//   - Each thread computes its OWN bases per row (redundant x4 o-groups; VALU
//     is cheap) -- no bases LDS, no scatter, no mid-kernel barrier.
//   - Dense 11-vector built in REGISTERS via a 4-way select chain (handles
//     out-of-range x for free: d outside [0,3] -> 0), so the 11-term dot uses
//     compile-time register indices.
//   - 8-row streaming loop per thread: load x (coalesced) -> 18 VALU weights
//     -> 88 select -> 44 FMA -> 4 coalesced stores. No inter-row dependencies.

#define BATCH    2048
#define IN_DIM   64
#define OUT_DIM  64
#define NCOEF    11
#define B_CHUNK  8
#define O_BLK    16                          // o's per block; thread owns 4
#define CTILE    (O_BLK * IN_DIM * NCOEF)    // 11264 floats = 44 KiB

__global__ __launch_bounds__(256) void kan_kernel(
    const float* __restrict__ x,     // (2048, 64)
    const float* __restrict__ grid,  // (64, 64, 15) broadcast uniform knots
    const float* __restrict__ coef,  // (64, 64, 11)
    float* __restrict__ out)         // (2048, 64, 64)
{
    __shared__ float clds[CTILE];    // 44 KiB

    const int tid    = threadIdx.x;
    const int o_tile = blockIdx.x & 3;            // 4 o-tiles of 16
    const int b0     = (blockIdx.x >> 2) * B_CHUNK;

    // ---- coef tile -> LDS: pure coalesced stride-1 copy, then ONE barrier ----
    const float* csrc = coef + (size_t)o_tile * CTILE;
    #pragma unroll
    for (int q = 0; q < CTILE / 256; ++q)
        clds[tid + q * 256] = csrc[tid + q * 256];

    const float g0    = grid[0];
    const float inv_h = 1.0f / (grid[1] - g0);

    __syncthreads();

    // ---- fill 44 coef regs (lane word-stride 11 = odd -> conflict-free) ----
    const int i    = tid & 63;
    const int ogrp = tid >> 6;                    // 0..3
    const int ol0  = ogrp * 4;                    // local o base (0,4,8,12)
    const int o0   = o_tile * O_BLK + ol0;

    float c[4][NCOEF];
    #pragma unroll
    for (int oo = 0; oo < 4; ++oo) {
        const int row = ((ol0 + oo) * IN_DIM + i) * NCOEF;
        #pragma unroll
        for (int t = 0; t < NCOEF; ++t)
            c[oo][t] = clds[row + t];
    }

    // ---- barrier-free streaming loop: 8 rows, fully independent ----
    #pragma unroll 2
    for (int bb = 0; bb < B_CHUNK; ++bb) {
        const float xv  = x[(size_t)(b0 + bb) * IN_DIM + i];
        const float pos = (xv - g0) * inv_h;          // cell coord in [0,14)
        const float fm  = floorf(pos);
        const float t   = pos - fm;
        // base = m-3; push out-of-domain lanes far away so every select -> 0
        const int   base = (pos >= 0.0f && pos < 14.0f) ? ((int)fm - 3) : -1000;

        const float t2 = t * t;
        const float t3 = t2 * t;
        const float s  = 1.0f - t;
        const float w0 = s * s * s * (1.0f / 6.0f);
        const float w1 = (3.0f * t3 - 6.0f * t2 + 4.0f) * (1.0f / 6.0f);
        const float w2 = (-3.0f * t3 + 3.0f * t2 + 3.0f * t + 1.0f) * (1.0f / 6.0f);
        const float w3 = t3 * (1.0f / 6.0f);

        // dense basis vector in registers (compile-time indices everywhere)
        float dense[NCOEF];
        #pragma unroll
        for (int tt = 0; tt < NCOEF; ++tt) {
            const int d = tt - base;
            dense[tt] = (d == 0) ? w0 : (d == 1) ? w1 : (d == 2) ? w2
                      : (d == 3) ? w3 : 0.0f;
        }

        float* op = &out[(size_t)(b0 + bb) * (OUT_DIM * IN_DIM) + o0 * IN_DIM + i];
        #pragma unroll
        for (int oo = 0; oo < 4; ++oo) {
            float acc = dense[0] * c[oo][0];
            #pragma unroll
            for (int tt = 1; tt < NCOEF; ++tt)
                acc += dense[tt] * c[oo][tt];
            op[oo * IN_DIM] = acc;
        }
    }
}

extern "C" void kernel_launch(void* const* d_in, const int* in_sizes, int n_in,
                              void* d_out, int out_size, void* d_ws, size_t ws_size,
                              hipStream_t stream) {
    const float* x    = (const float*)d_in[0];
    const float* grid = (const float*)d_in[1];
    const float* coef = (const float*)d_in[2];
    float* out = (float*)d_out;

    const int nblocks = (BATCH / B_CHUNK) * (OUT_DIM / O_BLK);  // 1024
    kan_kernel<<<nblocks, 256, 0, stream>>>(x, grid, coef, out);
}

// Round 8
// 17.335 us; speedup vs baseline: 1.0941x; 1.0928x over previous
//
#include <hip/hip_runtime.h>

// KAN activation: out[b,o,i] = sum_t B_t(x[b,i]) * coef[o,i,t]
// B=2048, IN=OUT=64, uniform knots (15), order k=3, 11 basis funcs.
//
// Round-8 thesis: rounds 2-6 all cluster at ~15us regardless of structure;
// the invariant is per-block startup (coef stage -> barrier -> reg fill
// latency chains) x block generations per CU. This version amortizes:
// B_TILE=32 rows per block (4 sub-chunks of 8 through a reused bases LDS),
// coef regs filled ONCE per 32 rows, grid 512 -> ~1 block generation per CU,
// 4x longer uninterrupted store stream per block (memset-like).
//
// Phase A (once): coef tile (8 o x 64 i x 11) staged via coalesced stride-1
//                 copy, 22 regs per thread filled from LDS (stride 11, free).
// Phase B (x4):   fill bases for 8 rows (2 (b,i) pairs/thread, analytic
//                 closed-form cubic weights, scatter into 3 float4 planes);
//                 barrier; consume 8 rows (3x ds_read_b128 + 22 FMA + 2
//                 coalesced dword stores per row); barrier.

#define BATCH    2048
#define IN_DIM   64
#define OUT_DIM  64
#define NCOEF    11
#define B_TILE   32                          // rows per block
#define B_SUB    8                           // rows per bases-LDS refill
#define O_TILE   8
#define NPAIR    (B_SUB * IN_DIM)            // 512
#define PLANE    (NPAIR * 4)                 // floats per basis plane
#define CTILE    (O_TILE * IN_DIM * NCOEF)   // 5632 floats = 22 KiB

__global__ __launch_bounds__(256) void kan_kernel(
    const float* __restrict__ x,     // (2048, 64)
    const float* __restrict__ grid,  // (64, 64, 15) broadcast uniform knots
    const float* __restrict__ coef,  // (64, 64, 11)
    float* __restrict__ out)         // (2048, 64, 64)
{
    __shared__ float bas_lds[3 * PLANE];   // 24 KiB (reused 4x)
    __shared__ float coef_lds[CTILE];      // 22 KiB

    const int tid    = threadIdx.x;
    const int o_tile = blockIdx.x & (OUT_DIM / O_TILE - 1);   // & 7
    const int b0     = (blockIdx.x >> 3) * B_TILE;

    // ---- Phase A: coef tile -> LDS (coalesced stride-1), once ----
    const float* csrc = coef + (size_t)o_tile * CTILE;
    #pragma unroll
    for (int q = 0; q < CTILE / 256; ++q)
        coef_lds[tid + q * 256] = csrc[tid + q * 256];

    const float g0    = grid[0];
    const float inv_h = 1.0f / (grid[1] - g0);

    __syncthreads();

    // coef regs filled ONCE, amortized over 32 rows
    const int i   = tid & 63;
    const int grp = tid >> 6;                  // 0..3
    const int ol0 = grp * 2;                   // local o
    const int o   = o_tile * O_TILE + ol0;

    float c[2][NCOEF];
    #pragma unroll
    for (int oo = 0; oo < 2; ++oo) {
        const int row = ((ol0 + oo) * IN_DIM + i) * NCOEF;  // stride 11: conflict-free
        #pragma unroll
        for (int t = 0; t < NCOEF; ++t)
            c[oo][t] = coef_lds[row + t];
    }

    // ---- Phase B: 4 sub-chunks of 8 rows through the bases LDS ----
    for (int sub = 0; sub < B_TILE / B_SUB; ++sub) {
        const int r0 = b0 + sub * B_SUB;

        // fill: 2 (b,i) pairs per thread
        #pragma unroll
        for (int qq = 0; qq < NPAIR / 256; ++qq) {
            const int p  = tid + qq * 256;          // p = rr*64 + ii
            const float xv = x[(size_t)(r0 + (p >> 6)) * IN_DIM + (p & 63)];

            const float4 z = make_float4(0.f, 0.f, 0.f, 0.f);
            *(float4*)&bas_lds[0 * PLANE + p * 4] = z;
            *(float4*)&bas_lds[1 * PLANE + p * 4] = z;
            *(float4*)&bas_lds[2 * PLANE + p * 4] = z;

            const float pos = (xv - g0) * inv_h;    // cell coord in [0,14)
            if (pos >= 0.0f && pos < 14.0f) {
                const int   m  = (int)pos;
                const float t  = pos - (float)m;
                const float t2 = t * t;
                const float t3 = t2 * t;
                const float s  = 1.0f - t;
                const float w0 = s * s * s * (1.0f / 6.0f);
                const float w1 = (3.0f * t3 - 6.0f * t2 + 4.0f) * (1.0f / 6.0f);
                const float w2 = (-3.0f * t3 + 3.0f * t2 + 3.0f * t + 1.0f) * (1.0f / 6.0f);
                const float w3 = t3 * (1.0f / 6.0f);

                const int mb = m - 3;
                int idx;
                idx = mb + 0; if ((unsigned)idx < NCOEF) bas_lds[(idx >> 2) * PLANE + p * 4 + (idx & 3)] = w0;
                idx = mb + 1; if ((unsigned)idx < NCOEF) bas_lds[(idx >> 2) * PLANE + p * 4 + (idx & 3)] = w1;
                idx = mb + 2; if ((unsigned)idx < NCOEF) bas_lds[(idx >> 2) * PLANE + p * 4 + (idx & 3)] = w2;
                idx = mb + 3; if ((unsigned)idx < NCOEF) bas_lds[(idx >> 2) * PLANE + p * 4 + (idx & 3)] = w3;
            }
        }
        __syncthreads();

        // consume: 8 rows, 2 outputs each
        #pragma unroll
        for (int rr = 0; rr < B_SUB; ++rr) {
            const int p = rr * IN_DIM + i;
            const float4 v0 = *(const float4*)&bas_lds[0 * PLANE + p * 4];
            const float4 v1 = *(const float4*)&bas_lds[1 * PLANE + p * 4];
            const float4 v2 = *(const float4*)&bas_lds[2 * PLANE + p * 4];

            float* op = &out[(size_t)(r0 + rr) * (OUT_DIM * IN_DIM) + o * IN_DIM + i];
            #pragma unroll
            for (int oo = 0; oo < 2; ++oo) {
                float acc;
                acc  = v0.x * c[oo][0] + v0.y * c[oo][1] + v0.z * c[oo][2] + v0.w * c[oo][3];
                acc += v1.x * c[oo][4] + v1.y * c[oo][5] + v1.z * c[oo][6] + v1.w * c[oo][7];
                acc += v2.x * c[oo][8] + v2.y * c[oo][9] + v2.z * c[oo][10];
                op[oo * IN_DIM] = acc;
            }
        }
        __syncthreads();   // before refilling bases
    }
}

extern "C" void kernel_launch(void* const* d_in, const int* in_sizes, int n_in,
                              void* d_out, int out_size, void* d_ws, size_t ws_size,
                              hipStream_t stream) {
    const float* x    = (const float*)d_in[0];
    const float* grid = (const float*)d_in[1];
    const float* coef = (const float*)d_in[2];
    float* out = (float*)d_out;

    const int nblocks = (BATCH / B_TILE) * (OUT_DIM / O_TILE);  // 512
    kan_kernel<<<nblocks, 256, 0, stream>>>(x, grid, coef, out);
}

// Round 9
// 14.415 us; speedup vs baseline: 1.3156x; 1.2025x over previous
//
#include <hip/hip_runtime.h>

// KAN activation: out[b,o,i] = sum_t B_t(x[b,i]) * coef[o,i,t]
// B=2048, IN=OUT=64, uniform knots (15), order k=3, 11 basis funcs.
//
// Round-9 thesis: all prior variants (14.7-17.3us) paid multiple block
// generations per CU, each a startup latency chain (coef stage -> barrier ->
// reg fill -> consume); reducing generations reduced co-residency and
// re-serialized. This version: EXACTLY ONE generation, ONE barrier.
//   grid = 256 blocks (1/CU), block = 1024 threads (16 waves = 4/SIMD)
//   per block: 16 batch rows x 32 output dims
//   LDS 136 KB = coef half (32 o x 64 i x 11 = 88 KB, coalesced stride-1
//   stage) + bases (16 rows x 64 i x 12 slots = 48 KB, float4 planes).
// After the barrier each thread streams 16 independent rows
// (3x ds_read_b128 + 22 FMA + 2x 256B coalesced stores) -- memset-like,
// no further sync. All LDS patterns <=2-way bank aliasing (free).

#define BATCH    2048
#define IN_DIM   64
#define OUT_DIM  64
#define NCOEF    11
#define B_TILE   16
#define O_HALF   32
#define NPAIR    (B_TILE * IN_DIM)           // 1024 (1 pair/thread)
#define PLANE    (NPAIR * 4)                 // floats per basis plane
#define CTILE    (O_HALF * IN_DIM * NCOEF)   // 22528 floats = 88 KiB

__global__ __launch_bounds__(1024) void kan_kernel(
    const float* __restrict__ x,     // (2048, 64)
    const float* __restrict__ grid,  // (64, 64, 15) broadcast uniform knots
    const float* __restrict__ coef,  // (64, 64, 11)
    float* __restrict__ out)         // (2048, 64, 64)
{
    __shared__ float coef_lds[CTILE];      // 88 KiB
    __shared__ float bas_lds[3 * PLANE];   // 48 KiB

    const int tid    = threadIdx.x;
    const int o_half = blockIdx.x & 1;
    const int b0     = (blockIdx.x >> 1) * B_TILE;

    // ---- x load first (bases depend on it) ----
    const int p = tid;                        // p = rr*64 + ii
    const float xv = x[(size_t)(b0 + (p >> 6)) * IN_DIM + (p & 63)];

    // ---- coef half-tile -> LDS: coalesced stride-1 copy (22/thread) ----
    const float* csrc = coef + (size_t)o_half * CTILE;
    #pragma unroll
    for (int q = 0; q < CTILE / 1024; ++q)
        coef_lds[tid + q * 1024] = csrc[tid + q * 1024];

    const float g0    = grid[0];
    const float inv_h = 1.0f / (grid[1] - g0);

    // ---- bases: closed-form cubic weights, 1 (b,i) pair per thread ----
    {
        const float4 z = make_float4(0.f, 0.f, 0.f, 0.f);
        *(float4*)&bas_lds[0 * PLANE + p * 4] = z;
        *(float4*)&bas_lds[1 * PLANE + p * 4] = z;
        *(float4*)&bas_lds[2 * PLANE + p * 4] = z;

        const float pos = (xv - g0) * inv_h;   // cell coord in [0,14)
        if (pos >= 0.0f && pos < 14.0f) {
            const int   m  = (int)pos;
            const float t  = pos - (float)m;
            const float t2 = t * t;
            const float t3 = t2 * t;
            const float s  = 1.0f - t;
            const float w0 = s * s * s * (1.0f / 6.0f);
            const float w1 = (3.0f * t3 - 6.0f * t2 + 4.0f) * (1.0f / 6.0f);
            const float w2 = (-3.0f * t3 + 3.0f * t2 + 3.0f * t + 1.0f) * (1.0f / 6.0f);
            const float w3 = t3 * (1.0f / 6.0f);

            const int mb = m - 3;
            int idx;
            idx = mb + 0; if ((unsigned)idx < NCOEF) bas_lds[(idx >> 2) * PLANE + p * 4 + (idx & 3)] = w0;
            idx = mb + 1; if ((unsigned)idx < NCOEF) bas_lds[(idx >> 2) * PLANE + p * 4 + (idx & 3)] = w1;
            idx = mb + 2; if ((unsigned)idx < NCOEF) bas_lds[(idx >> 2) * PLANE + p * 4 + (idx & 3)] = w2;
            idx = mb + 3; if ((unsigned)idx < NCOEF) bas_lds[(idx >> 2) * PLANE + p * 4 + (idx & 3)] = w3;
        }
    }
    __syncthreads();   // the ONLY barrier

    // ---- coef regs: 22 from LDS (lane word-stride 11 = odd -> free) ----
    const int i   = tid & 63;
    const int grp = tid >> 6;                  // 0..15
    const int ol0 = grp * 2;                   // local o within the half
    const int o   = o_half * O_HALF + ol0;

    float c[2][NCOEF];
    #pragma unroll
    for (int oo = 0; oo < 2; ++oo) {
        const int row = ((ol0 + oo) * IN_DIM + i) * NCOEF;
        #pragma unroll
        for (int t = 0; t < NCOEF; ++t)
            c[oo][t] = coef_lds[row + t];
    }

    // ---- stream 16 independent rows: no sync, memset-like ----
    float* op0 = &out[(size_t)b0 * (OUT_DIM * IN_DIM) + o * IN_DIM + i];
    #pragma unroll 4
    for (int rr = 0; rr < B_TILE; ++rr) {
        const int pp = rr * IN_DIM + i;
        const float4 v0 = *(const float4*)&bas_lds[0 * PLANE + pp * 4];
        const float4 v1 = *(const float4*)&bas_lds[1 * PLANE + pp * 4];
        const float4 v2 = *(const float4*)&bas_lds[2 * PLANE + pp * 4];

        float* op = op0 + (size_t)rr * (OUT_DIM * IN_DIM);
        #pragma unroll
        for (int oo = 0; oo < 2; ++oo) {
            float acc;
            acc  = v0.x * c[oo][0] + v0.y * c[oo][1] + v0.z * c[oo][2] + v0.w * c[oo][3];
            acc += v1.x * c[oo][4] + v1.y * c[oo][5] + v1.z * c[oo][6] + v1.w * c[oo][7];
            acc += v2.x * c[oo][8] + v2.y * c[oo][9] + v2.z * c[oo][10];
            op[oo * IN_DIM] = acc;
        }
    }
}

extern "C" void kernel_launch(void* const* d_in, const int* in_sizes, int n_in,
                              void* d_out, int out_size, void* d_ws, size_t ws_size,
                              hipStream_t stream) {
    const float* x    = (const float*)d_in[0];
    const float* grid = (const float*)d_in[1];
    const float* coef = (const float*)d_in[2];
    float* out = (float*)d_out;

    const int nblocks = (BATCH / B_TILE) * 2;   // 256 = 1 block/CU
    kan_kernel<<<nblocks, 1024, 0, stream>>>(x, grid, coef, out);
}